// Round 10
// baseline (509.671 us; speedup 1.0000x reference)
//
#include <hip/hip_runtime.h>
#include <hip/hip_fp16.h>
#include <math.h>

#define N_NODES    100000
#define N_PATHS    1600000
#define PATH_SZ    3
#define IN_SZ      64
#define HID        32
#define EMB_STRIDE 96          // PATH_SZ * HID (halves)
#define EPS_F      1e-4f

// ---- static device scratch ----
__device__ __half g_embh[(size_t)N_NODES * EMB_STRIDE];  // 19.2 MB fp16
__device__ float  g_M[HID * HID];                        // gram^{-1/2}
__device__ int    g_offs[N_NODES];

// ---------------- fused single-block prefix scan: ksz -> g_offs ----------------
#define SCT 1024
#define SCI ((N_NODES + SCT - 1) / SCT)    // 98

__global__ __launch_bounds__(SCT) void k_scan(const int* __restrict__ ksz) {
    __shared__ int ws[SCT];
    int t = threadIdx.x;
    int base = t * SCI;
    int s = 0;
    for (int u = 0; u < SCI; u++) {
        int idx = base + u;
        if (idx < N_NODES) s += ksz[idx];
    }
    ws[t] = s;
    __syncthreads();
    // Hillis-Steele inclusive scan over 1024 thread sums
    for (int d = 1; d < SCT; d <<= 1) {
        int a = (t >= d) ? ws[t - d] : 0;
        __syncthreads();
        ws[t] += a;
        __syncthreads();
    }
    int run = ws[t] - s;                   // exclusive prefix
    for (int u = 0; u < SCI; u++) {
        int idx = base + u;
        if (idx < N_NODES) { g_offs[idx] = run; run += ksz[idx]; }
    }
}

// ---------------- gram + coupled Newton-Schulz -> g_M (single block) ----------------
// G = I + E, off-diag ~ e^-4 => spectrum ~[0.97,1.56] => 6 NS iters to fp32 precision.
struct ShJ {
    float w[96 * 65];
    float Y[32 * 33];
    float Z[32 * 33];
    float P[32 * 33];
};

__global__ __launch_bounds__(256) void k_ns(const float* __restrict__ W) {
    __shared__ ShJ sh;
    int t = threadIdx.x;

    for (int idx = t; idx < 96 * 64; idx += 256) {
        int r = idx >> 6, c = idx & 63;
        sh.w[r * 65 + c] = W[idx];
    }
    __syncthreads();
#pragma unroll
    for (int u = 0; u < 4; u++) {
        int e = t * 4 + u;
        int h = e >> 5, g = e & 31;
        float d = 0.f;
        for (int pi = 0; pi < 3; pi++) {
            const float* r0 = &sh.w[(h * 3 + pi) * 65];
            const float* r1 = &sh.w[(g * 3 + pi) * 65];
#pragma unroll
            for (int i = 0; i < 64; i++) d = fmaf(r0[i], r1[i], d);
        }
        sh.Y[h * 33 + g] = __expf(fmaf(d, 4.0f / 3.0f, -4.0f));
        sh.Z[h * 33 + g] = (h == g) ? 1.0f : 0.0f;
    }
    __syncthreads();
    for (int it = 0; it < 6; it++) {
#pragma unroll
        for (int u = 0; u < 4; u++) {
            int e = t * 4 + u;
            int i = e >> 5, j = e & 31;
            float p = 0.f;
#pragma unroll
            for (int k = 0; k < 32; k++)
                p = fmaf(sh.Z[i * 33 + k], sh.Y[k * 33 + j], p);
            sh.P[i * 33 + j] = p;
        }
        __syncthreads();
        float U[4], V[4];
#pragma unroll
        for (int u = 0; u < 4; u++) {
            int e = t * 4 + u;
            int i = e >> 5, j = e & 31;
            float su = 0.f, sv = 0.f;
#pragma unroll
            for (int k = 0; k < 32; k++) {
                float Tkj = -0.5f * sh.P[k * 33 + j]; if (k == j) Tkj += 1.5f;
                float Tik = -0.5f * sh.P[i * 33 + k]; if (i == k) Tik += 1.5f;
                su = fmaf(sh.Y[i * 33 + k], Tkj, su);
                sv = fmaf(Tik, sh.Z[k * 33 + j], sv);
            }
            U[u] = su; V[u] = sv;
        }
        __syncthreads();
#pragma unroll
        for (int u = 0; u < 4; u++) {
            int e = t * 4 + u;
            int i = e >> 5, j = e & 31;
            sh.Y[i * 33 + j] = U[u];
            sh.Z[i * 33 + j] = V[u];
        }
        __syncthreads();
    }
#pragma unroll
    for (int u = 0; u < 4; u++) {
        int e = t * 4 + u;
        g_M[e] = sh.Z[(e >> 5) * 33 + (e & 31)];
    }
}

// ---------------- emb GEMM: one thread per node; W thread-invariant -> s_load ----------------
__global__ __launch_bounds__(256) void k_emb(const float* __restrict__ feat,
                                             const float* __restrict__ W) {
    int n = blockIdx.x * 256 + threadIdx.x;
    if (n >= N_NODES) return;

    float x[64];
    const float4* f4 = reinterpret_cast<const float4*>(feat + (size_t)n * 64);
#pragma unroll
    for (int c = 0; c < 16; c++) {
        float4 v = f4[c];
        x[c * 4 + 0] = v.x; x[c * 4 + 1] = v.y; x[c * 4 + 2] = v.z; x[c * 4 + 3] = v.w;
    }
    float ssum = 0.f;
#pragma unroll
    for (int i = 0; i < 64; i++) ssum = fmaf(x[i], x[i], ssum);
    float inv = 1.0f / fmaxf(sqrtf(ssum), EPS_F);
#pragma unroll
    for (int i = 0; i < 64; i++) x[i] *= inv;      // normalize once

#pragma unroll
    for (int p = 0; p < 3; p++) {                  // FULL unroll: everything static
        float a[32];
#pragma unroll
        for (int h = 0; h < 32; h++) {
            const float* wr = W + ((h * 3 + p) << 6);   // thread-invariant -> s_load
            float d = 0.f;
#pragma unroll
            for (int i = 0; i < 64; i++) d = fmaf(x[i], wr[i], d);
            a[h] = d;
        }
        // pack 32 halves into 4x int4 via bit-ops (no local-array reinterpret)
        unsigned int u[16];
#pragma unroll
        for (int k = 0; k < 16; k++) {
            unsigned int lo = __half_as_ushort(__float2half(a[2 * k]));
            unsigned int hi = __half_as_ushort(__float2half(a[2 * k + 1]));
            u[k] = (hi << 16) | lo;
        }
        int4* dst = reinterpret_cast<int4*>(&g_embh[(size_t)n * EMB_STRIDE + p * HID]);
        dst[0] = make_int4(u[0],  u[1],  u[2],  u[3]);
        dst[1] = make_int4(u[4],  u[5],  u[6],  u[7]);
        dst[2] = make_int4(u[8],  u[9],  u[10], u[11]);
        dst[3] = make_int4(u[12], u[13], u[14], u[15]);
    }
}

// ---------------- gather + kappa + segment-sum + whiten (wave per node) ----------------
__global__ __launch_bounds__(256) void k_pool(const int* __restrict__ paths,
                                              const int* __restrict__ ksz,
                                              float* __restrict__ out) {
    __shared__ float Ml[HID * HID];
    for (int idx = threadIdx.x; idx < HID * HID; idx += 256) Ml[idx] = g_M[idx];
    __syncthreads();

    int lane = threadIdx.x & 63;
    int half = lane >> 5;
    int j = lane & 31;
    int node = blockIdx.x * 4 + (threadIdx.x >> 6);   // grid exactly N_NODES/4 blocks
    const __half* eb = g_embh;

    int off = g_offs[node];
    int ks  = ksz[node];
    float pooled = 0.f;

    if (ks == 16) {
        // fast path: half-wave owns 8 paths; all 24 gathers issued before any consume
        const int* pb = paths + (size_t)(off + (half << 3)) * 3;
        int ix[24];
#pragma unroll
        for (int u = 0; u < 24; u++) ix[u] = pb[u];
        __half v0[8], v1[8], v2[8];
#pragma unroll
        for (int q = 0; q < 8; q++) {
            v0[q] = eb[(size_t)ix[3 * q + 0] * EMB_STRIDE + j];
            v1[q] = eb[(size_t)ix[3 * q + 1] * EMB_STRIDE + HID + j];
            v2[q] = eb[(size_t)ix[3 * q + 2] * EMB_STRIDE + 2 * HID + j];
        }
#pragma unroll
        for (int q = 0; q < 8; q++) {
            float e = __half2float(v0[q]) + __half2float(v1[q]) + __half2float(v2[q]);
            pooled += __expf(fmaf(e, 4.0f / 3.0f, -4.0f));
        }
    } else {
        // generic path (exact repeat/segment semantics for any ks)
        for (int pi = half; pi < ks; pi += 2) {
            size_t pp = (size_t)(off + pi) * 3;
            int i0 = paths[pp + 0], i1 = paths[pp + 1], i2 = paths[pp + 2];
            float e = __half2float(eb[(size_t)i0 * EMB_STRIDE + j])
                    + __half2float(eb[(size_t)i1 * EMB_STRIDE + HID + j])
                    + __half2float(eb[(size_t)i2 * EMB_STRIDE + 2 * HID + j]);
            pooled += __expf(fmaf(e, 4.0f / 3.0f, -4.0f));
        }
    }

    pooled += __shfl_xor(pooled, 32);       // combine the two half-waves
    // whiten: out[node][j] = sum_k pooled[k] * M[k][j]
    float o = 0.f;
#pragma unroll
    for (int k = 0; k < 32; k++)
        o = fmaf(__shfl(pooled, k), Ml[k * 32 + j], o);
    if (half == 0) out[(size_t)node * HID + j] = o;
}

extern "C" void kernel_launch(void* const* d_in, const int* in_sizes, int n_in,
                              void* d_out, int out_size, void* d_ws, size_t ws_size,
                              hipStream_t stream) {
    const float* feat  = (const float*)d_in[0];
    const int*   paths = (const int*)d_in[1];
    const int*   ksz   = (const int*)d_in[2];
    const float* W     = (const float*)d_in[3];
    float*       out   = (float*)d_out;

    k_scan<<<1, SCT, 0, stream>>>(ksz);
    k_ns<<<1, 256, 0, stream>>>(W);
    k_emb<<<(N_NODES + 255) / 256, 256, 0, stream>>>(feat, W);
    k_pool<<<N_NODES / 4, 256, 0, stream>>>(paths, ksz, out);
}

// Round 12
// 286.121 us; speedup vs baseline: 1.7813x; 1.7813x over previous
//
#include <hip/hip_runtime.h>
#include <hip/hip_fp16.h>
#include <math.h>

#define N_NODES    100000
#define N_PATHS    1600000
#define PATH_SZ    3
#define IN_SZ      64
#define HID        32
#define EMB_STRIDE 96          // PATH_SZ * HID (halves)
#define EPS_F      1e-4f

#define SCAN_TPB   256
#define SCAN_IPT   8
#define SCAN_CHUNK (SCAN_TPB * SCAN_IPT)                        // 2048
#define SCAN_NB    ((N_NODES + SCAN_CHUNK - 1) / SCAN_CHUNK)   // 49

// ---- static device scratch ----
__device__ __half g_embh[(size_t)N_NODES * EMB_STRIDE];  // 19.2 MB fp16
__device__ float  g_M[HID * HID];                        // gram^{-1/2}
__device__ int    g_offs[N_NODES];
__device__ int    g_bsum[SCAN_NB];
__device__ int    g_boff[SCAN_NB];

// ---------------- multi-block prefix-sum of kernel_size -> g_offs ----------------
__global__ __launch_bounds__(SCAN_TPB) void k_scan1(const int* __restrict__ ksz) {
    __shared__ int red[SCAN_TPB];
    int b = blockIdx.x, t = threadIdx.x;
    int base = b * SCAN_CHUNK + t * SCAN_IPT;
    int s = 0;
#pragma unroll
    for (int u = 0; u < SCAN_IPT; u++) {
        int idx = base + u;
        if (idx < N_NODES) s += ksz[idx];
    }
    red[t] = s;
    __syncthreads();
    for (int d = SCAN_TPB >> 1; d > 0; d >>= 1) {
        if (t < d) red[t] += red[t + d];
        __syncthreads();
    }
    if (t == 0) g_bsum[b] = red[0];
}

__global__ void k_scan2() {
    if (threadIdx.x == 0) {
        int run = 0;
        for (int b = 0; b < SCAN_NB; b++) { g_boff[b] = run; run += g_bsum[b]; }
    }
}

__global__ __launch_bounds__(SCAN_TPB) void k_scan3(const int* __restrict__ ksz) {
    __shared__ int sc[SCAN_TPB];
    int b = blockIdx.x, t = threadIdx.x;
    int base = b * SCAN_CHUNK + t * SCAN_IPT;
    int v[SCAN_IPT];
    int s = 0;
#pragma unroll
    for (int u = 0; u < SCAN_IPT; u++) {
        int idx = base + u;
        v[u] = (idx < N_NODES) ? ksz[idx] : 0;
        s += v[u];
    }
    sc[t] = s;
    __syncthreads();
    for (int d = 1; d < SCAN_TPB; d <<= 1) {
        int a = (t >= d) ? sc[t - d] : 0;
        __syncthreads();
        sc[t] += a;
        __syncthreads();
    }
    int incl = sc[t];
    int run = g_boff[b] + (incl - s);   // exclusive prefix for this thread
#pragma unroll
    for (int u = 0; u < SCAN_IPT; u++) {
        int idx = base + u;
        if (idx < N_NODES) g_offs[idx] = run;
        run += v[u];
    }
}

// ---------------- fused: emb GEMM (blocks>=1, W in LDS) + gram/NS (block 0) ----------------
union ShE {
    float w[96 * 64];                  // emb blocks: unpadded, uniform-broadcast reads
    struct {
        float w[96 * 68];              // gram: stride-68 rows (272 B, 16B-aligned f4 reads)
        float Y[32 * 36];              // stride-36 (144 B, 16B-aligned)
        float Z[32 * 36];
        float P[32 * 36];
    } j;
};

__global__ __launch_bounds__(256) void k_embns(const float* __restrict__ feat,
                                               const float* __restrict__ W) {
    __shared__ ShE sh;
    int t = threadIdx.x;

    if (blockIdx.x == 0) {
        // ---- stage W padded (stride 68) ----
        for (int idx = t; idx < 96 * 64; idx += 256) {
            int r = idx >> 6, c = idx & 63;
            sh.j.w[r * 68 + c] = W[idx];
        }
        __syncthreads();
        // ---- gram = kappa(W.Wt/3) into Y; Z = I ----
#pragma unroll
        for (int u = 0; u < 4; u++) {
            int e = t * 4 + u;
            int h = e >> 5, g = e & 31;
            float d = 0.f;
            for (int pi = 0; pi < 3; pi++) {
                const float4* r0 = reinterpret_cast<const float4*>(&sh.j.w[(h * 3 + pi) * 68]);
                const float4* r1 = reinterpret_cast<const float4*>(&sh.j.w[(g * 3 + pi) * 68]);
#pragma unroll
                for (int i = 0; i < 16; i++) {
                    float4 a = r0[i], b = r1[i];
                    d = fmaf(a.x, b.x, d); d = fmaf(a.y, b.y, d);
                    d = fmaf(a.z, b.z, d); d = fmaf(a.w, b.w, d);
                }
            }
            sh.j.Y[h * 36 + g] = __expf(fmaf(d, 4.0f / 3.0f, -4.0f));
            sh.j.Z[h * 36 + g] = (h == g) ? 1.0f : 0.0f;
        }
        __syncthreads();
        // ---- coupled NS, 5 iters: P=Z*Y; Y<-1.5Y-0.5*(Y*P); Z<-1.5Z-0.5*(P*Z) ----
        for (int it = 0; it < 5; it++) {
#pragma unroll
            for (int u = 0; u < 4; u++) {
                int e = t * 4 + u;
                int i = e >> 5, j = e & 31;
                const float4* zr = reinterpret_cast<const float4*>(&sh.j.Z[i * 36]);
                float p = 0.f;
#pragma unroll
                for (int k8 = 0; k8 < 8; k8++) {
                    float4 z4 = zr[k8];
                    int k = k8 * 4;
                    p = fmaf(z4.x, sh.j.Y[(k + 0) * 36 + j], p);
                    p = fmaf(z4.y, sh.j.Y[(k + 1) * 36 + j], p);
                    p = fmaf(z4.z, sh.j.Y[(k + 2) * 36 + j], p);
                    p = fmaf(z4.w, sh.j.Y[(k + 3) * 36 + j], p);
                }
                sh.j.P[i * 36 + j] = p;
            }
            __syncthreads();
            float U[4], V[4];
#pragma unroll
            for (int u = 0; u < 4; u++) {
                int e = t * 4 + u;
                int i = e >> 5, j = e & 31;
                const float4* yr = reinterpret_cast<const float4*>(&sh.j.Y[i * 36]);
                const float4* pr = reinterpret_cast<const float4*>(&sh.j.P[i * 36]);
                float su = 0.f, sv = 0.f;
#pragma unroll
                for (int k8 = 0; k8 < 8; k8++) {
                    float4 y4 = yr[k8], p4 = pr[k8];
                    int k = k8 * 4;
                    su = fmaf(y4.x, sh.j.P[(k + 0) * 36 + j], su);
                    su = fmaf(y4.y, sh.j.P[(k + 1) * 36 + j], su);
                    su = fmaf(y4.z, sh.j.P[(k + 2) * 36 + j], su);
                    su = fmaf(y4.w, sh.j.P[(k + 3) * 36 + j], su);
                    sv = fmaf(p4.x, sh.j.Z[(k + 0) * 36 + j], sv);
                    sv = fmaf(p4.y, sh.j.Z[(k + 1) * 36 + j], sv);
                    sv = fmaf(p4.z, sh.j.Z[(k + 2) * 36 + j], sv);
                    sv = fmaf(p4.w, sh.j.Z[(k + 3) * 36 + j], sv);
                }
                U[u] = fmaf(-0.5f, su, 1.5f * sh.j.Y[i * 36 + j]);
                V[u] = fmaf(-0.5f, sv, 1.5f * sh.j.Z[i * 36 + j]);
            }
            __syncthreads();
#pragma unroll
            for (int u = 0; u < 4; u++) {
                int e = t * 4 + u;
                int i = e >> 5, j = e & 31;
                sh.j.Y[i * 36 + j] = U[u];
                sh.j.Z[i * 36 + j] = V[u];
            }
            __syncthreads();
        }
#pragma unroll
        for (int u = 0; u < 4; u++) {
            int e = t * 4 + u;
            g_M[e] = sh.j.Z[(e >> 5) * 36 + (e & 31)];
        }
        return;
    }

    // ---------------- emb blocks: W staged in LDS, one node per thread ----------------
    for (int idx = t; idx < 96 * 64; idx += 256) sh.w[idx] = W[idx];
    __syncthreads();

    int n = (blockIdx.x - 1) * 256 + t;
    if (n >= N_NODES) return;          // no barriers after this point

    float x[64];
    const float4* f4 = reinterpret_cast<const float4*>(feat + (size_t)n * 64);
#pragma unroll
    for (int c = 0; c < 16; c++) {
        float4 v = f4[c];
        x[c * 4 + 0] = v.x; x[c * 4 + 1] = v.y; x[c * 4 + 2] = v.z; x[c * 4 + 3] = v.w;
    }
    float ssum = 0.f;
#pragma unroll
    for (int i = 0; i < 64; i++) ssum = fmaf(x[i], x[i], ssum);
    float inv = 1.0f / fmaxf(sqrtf(ssum), EPS_F);
#pragma unroll
    for (int i = 0; i < 64; i++) x[i] *= inv;      // normalize once

#pragma unroll
    for (int p = 0; p < 3; p++) {                  // full unroll: all indexing static
        float a[32];
#pragma unroll
        for (int h = 0; h < 32; h++) {
            const float4* wr = reinterpret_cast<const float4*>(&sh.w[(h * 3 + p) << 6]);
            float d = 0.f;
#pragma unroll
            for (int i = 0; i < 16; i++) {
                float4 w4 = wr[i];                 // uniform-broadcast LDS read
                d = fmaf(x[i * 4 + 0], w4.x, d);
                d = fmaf(x[i * 4 + 1], w4.y, d);
                d = fmaf(x[i * 4 + 2], w4.z, d);
                d = fmaf(x[i * 4 + 3], w4.w, d);
            }
            a[h] = d;
        }
        unsigned int u[16];
#pragma unroll
        for (int k = 0; k < 16; k++) {
            unsigned int lo = __half_as_ushort(__float2half(a[2 * k]));
            unsigned int hi = __half_as_ushort(__float2half(a[2 * k + 1]));
            u[k] = (hi << 16) | lo;
        }
        int4* dst = reinterpret_cast<int4*>(&g_embh[(size_t)n * EMB_STRIDE + p * HID]);
        dst[0] = make_int4(u[0],  u[1],  u[2],  u[3]);
        dst[1] = make_int4(u[4],  u[5],  u[6],  u[7]);
        dst[2] = make_int4(u[8],  u[9],  u[10], u[11]);
        dst[3] = make_int4(u[12], u[13], u[14], u[15]);
    }
}

// ---------------- gather + kappa + segment-sum + whiten (wave per node) ----------------
__global__ __launch_bounds__(256) void k_pool(const int* __restrict__ paths,
                                              const int* __restrict__ ksz,
                                              float* __restrict__ out) {
    __shared__ float Ml[HID * HID];
    for (int idx = threadIdx.x; idx < HID * HID; idx += 256) Ml[idx] = g_M[idx];
    __syncthreads();

    int lane = threadIdx.x & 63;
    int half = lane >> 5;
    int j = lane & 31;
    int node = blockIdx.x * 4 + (threadIdx.x >> 6);   // grid exactly N_NODES/4 blocks
    const __half* eb = g_embh;

    int off = g_offs[node];
    int ks  = ksz[node];
    float pooled = 0.f;

    if (ks == 16) {
        // fast path: half-wave owns 8 paths; all 24 gathers issued before any consume
        const int* pb = paths + (size_t)(off + (half << 3)) * 3;
        int ix[24];
#pragma unroll
        for (int u = 0; u < 24; u++) ix[u] = pb[u];
        __half v0[8], v1[8], v2[8];
#pragma unroll
        for (int q = 0; q < 8; q++) {
            v0[q] = eb[(size_t)ix[3 * q + 0] * EMB_STRIDE + j];
            v1[q] = eb[(size_t)ix[3 * q + 1] * EMB_STRIDE + HID + j];
            v2[q] = eb[(size_t)ix[3 * q + 2] * EMB_STRIDE + 2 * HID + j];
        }
#pragma unroll
        for (int q = 0; q < 8; q++) {
            float e = __half2float(v0[q]) + __half2float(v1[q]) + __half2float(v2[q]);
            pooled += __expf(fmaf(e, 4.0f / 3.0f, -4.0f));
        }
    } else {
        // generic path (exact repeat/segment semantics for any ks)
        for (int pi = half; pi < ks; pi += 2) {
            size_t pp = (size_t)(off + pi) * 3;
            int i0 = paths[pp + 0], i1 = paths[pp + 1], i2 = paths[pp + 2];
            float e = __half2float(eb[(size_t)i0 * EMB_STRIDE + j])
                    + __half2float(eb[(size_t)i1 * EMB_STRIDE + HID + j])
                    + __half2float(eb[(size_t)i2 * EMB_STRIDE + 2 * HID + j]);
            pooled += __expf(fmaf(e, 4.0f / 3.0f, -4.0f));
        }
    }

    pooled += __shfl_xor(pooled, 32);       // combine the two half-waves
    // whiten: out[node][j] = sum_k pooled[k] * M[k][j]
    float o = 0.f;
#pragma unroll
    for (int k = 0; k < 32; k++)
        o = fmaf(__shfl(pooled, k), Ml[k * 32 + j], o);
    if (half == 0) out[(size_t)node * HID + j] = o;
}

extern "C" void kernel_launch(void* const* d_in, const int* in_sizes, int n_in,
                              void* d_out, int out_size, void* d_ws, size_t ws_size,
                              hipStream_t stream) {
    const float* feat  = (const float*)d_in[0];
    const int*   paths = (const int*)d_in[1];
    const int*   ksz   = (const int*)d_in[2];
    const float* W     = (const float*)d_in[3];
    float*       out   = (float*)d_out;

    k_scan1<<<SCAN_NB, SCAN_TPB, 0, stream>>>(ksz);
    k_scan2<<<1, 64, 0, stream>>>();
    k_scan3<<<SCAN_NB, SCAN_TPB, 0, stream>>>(ksz);

    int embBlocks = (N_NODES + 255) / 256;          // 391
    k_embns<<<embBlocks + 1, 256, 0, stream>>>(feat, W);

    k_pool<<<N_NODES / 4, 256, 0, stream>>>(paths, ksz, out);
}

// Round 13
// 269.633 us; speedup vs baseline: 1.8902x; 1.0611x over previous
//
#include <hip/hip_runtime.h>
#include <hip/hip_fp16.h>
#include <math.h>

#define N_NODES    100000
#define N_PATHS    1600000
#define PATH_SZ    3
#define IN_SZ      64
#define HID        32
#define EMB_STRIDE 96          // PATH_SZ * HID (halves)
#define EPS_F      1e-4f

#define SCAN_TPB   256
#define SCAN_IPT   8
#define SCAN_CHUNK (SCAN_TPB * SCAN_IPT)                        // 2048
#define SCAN_NB    ((N_NODES + SCAN_CHUNK - 1) / SCAN_CHUNK)   // 49

#define NODE_BLKS  ((N_NODES + 63) / 64)                       // 1563
#define EMB_WAVES  (NODE_BLKS * 3)                             // 4689
#define EMB_BLOCKS ((EMB_WAVES + 3) / 4)                       // 1173

// ---- static device scratch ----
__device__ __half g_embh[(size_t)N_NODES * EMB_STRIDE];  // 19.2 MB fp16
__device__ float  g_M[HID * HID];                        // gram^{-1/2}
__device__ int    g_offs[N_NODES];
__device__ int    g_bsum[SCAN_NB];
__device__ int    g_boff[SCAN_NB];

// ---------------- multi-block prefix-sum of kernel_size -> g_offs ----------------
__global__ __launch_bounds__(SCAN_TPB) void k_scan1(const int* __restrict__ ksz) {
    __shared__ int red[SCAN_TPB];
    int b = blockIdx.x, t = threadIdx.x;
    int base = b * SCAN_CHUNK + t * SCAN_IPT;
    int s = 0;
#pragma unroll
    for (int u = 0; u < SCAN_IPT; u++) {
        int idx = base + u;
        if (idx < N_NODES) s += ksz[idx];
    }
    red[t] = s;
    __syncthreads();
    for (int d = SCAN_TPB >> 1; d > 0; d >>= 1) {
        if (t < d) red[t] += red[t + d];
        __syncthreads();
    }
    if (t == 0) g_bsum[b] = red[0];
}

// 64-lane shuffle scan over the 49 block sums (was a 1-thread serial loop)
__global__ void k_scan2() {
    int t = threadIdx.x;                 // 64 threads
    int v = (t < SCAN_NB) ? g_bsum[t] : 0;
    int orig = v;
#pragma unroll
    for (int d = 1; d < 64; d <<= 1) {
        int o = __shfl_up(v, d);
        if (t >= d) v += o;
    }
    if (t < SCAN_NB) g_boff[t] = v - orig;   // exclusive prefix
}

__global__ __launch_bounds__(SCAN_TPB) void k_scan3(const int* __restrict__ ksz) {
    __shared__ int sc[SCAN_TPB];
    int b = blockIdx.x, t = threadIdx.x;
    int base = b * SCAN_CHUNK + t * SCAN_IPT;
    int v[SCAN_IPT];
    int s = 0;
#pragma unroll
    for (int u = 0; u < SCAN_IPT; u++) {
        int idx = base + u;
        v[u] = (idx < N_NODES) ? ksz[idx] : 0;
        s += v[u];
    }
    sc[t] = s;
    __syncthreads();
    for (int d = 1; d < SCAN_TPB; d <<= 1) {
        int a = (t >= d) ? sc[t - d] : 0;
        __syncthreads();
        sc[t] += a;
        __syncthreads();
    }
    int incl = sc[t];
    int run = g_boff[b] + (incl - s);   // exclusive prefix for this thread
#pragma unroll
    for (int u = 0; u < SCAN_IPT; u++) {
        int idx = base + u;
        if (idx < N_NODES) g_offs[idx] = run;
        run += v[u];
    }
}

// ---------------- fused: emb GEMM (blocks>=1, (node,p)-wave split) + gram/NS (block 0) ----------------
union ShE {
    float w[96 * 64];                  // emb blocks: unpadded, uniform-broadcast reads
    struct {
        float w[96 * 68];              // gram: stride-68 rows (272 B, 16B-aligned f4 reads)
        float Y[32 * 36];              // stride-36 (144 B, 16B-aligned)
        float Z[32 * 36];
        float P[32 * 36];
    } j;
};

__global__ __launch_bounds__(256) void k_embns(const float* __restrict__ feat,
                                               const float* __restrict__ W) {
    __shared__ ShE sh;
    int t = threadIdx.x;

    if (blockIdx.x == 0) {
        // ---- stage W padded (stride 68) ----
        for (int idx = t; idx < 96 * 64; idx += 256) {
            int r = idx >> 6, c = idx & 63;
            sh.j.w[r * 68 + c] = W[idx];
        }
        __syncthreads();
        // ---- gram = kappa(W.Wt/3) into Y; Z = I ----
#pragma unroll
        for (int u = 0; u < 4; u++) {
            int e = t * 4 + u;
            int h = e >> 5, g = e & 31;
            float d = 0.f;
            for (int pi = 0; pi < 3; pi++) {
                const float4* r0 = reinterpret_cast<const float4*>(&sh.j.w[(h * 3 + pi) * 68]);
                const float4* r1 = reinterpret_cast<const float4*>(&sh.j.w[(g * 3 + pi) * 68]);
#pragma unroll
                for (int i = 0; i < 16; i++) {
                    float4 a = r0[i], b = r1[i];
                    d = fmaf(a.x, b.x, d); d = fmaf(a.y, b.y, d);
                    d = fmaf(a.z, b.z, d); d = fmaf(a.w, b.w, d);
                }
            }
            sh.j.Y[h * 36 + g] = __expf(fmaf(d, 4.0f / 3.0f, -4.0f));
            sh.j.Z[h * 36 + g] = (h == g) ? 1.0f : 0.0f;
        }
        __syncthreads();
        // ---- coupled NS, 5 iters: P=Z*Y; Y<-1.5Y-0.5*(Y*P); Z<-1.5Z-0.5*(P*Z) ----
        for (int it = 0; it < 5; it++) {
#pragma unroll
            for (int u = 0; u < 4; u++) {
                int e = t * 4 + u;
                int i = e >> 5, j = e & 31;
                const float4* zr = reinterpret_cast<const float4*>(&sh.j.Z[i * 36]);
                float p = 0.f;
#pragma unroll
                for (int k8 = 0; k8 < 8; k8++) {
                    float4 z4 = zr[k8];
                    int k = k8 * 4;
                    p = fmaf(z4.x, sh.j.Y[(k + 0) * 36 + j], p);
                    p = fmaf(z4.y, sh.j.Y[(k + 1) * 36 + j], p);
                    p = fmaf(z4.z, sh.j.Y[(k + 2) * 36 + j], p);
                    p = fmaf(z4.w, sh.j.Y[(k + 3) * 36 + j], p);
                }
                sh.j.P[i * 36 + j] = p;
            }
            __syncthreads();
            float U[4], V[4];
#pragma unroll
            for (int u = 0; u < 4; u++) {
                int e = t * 4 + u;
                int i = e >> 5, j = e & 31;
                const float4* yr = reinterpret_cast<const float4*>(&sh.j.Y[i * 36]);
                const float4* pr = reinterpret_cast<const float4*>(&sh.j.P[i * 36]);
                float su = 0.f, sv = 0.f;
#pragma unroll
                for (int k8 = 0; k8 < 8; k8++) {
                    float4 y4 = yr[k8], p4 = pr[k8];
                    int k = k8 * 4;
                    su = fmaf(y4.x, sh.j.P[(k + 0) * 36 + j], su);
                    su = fmaf(y4.y, sh.j.P[(k + 1) * 36 + j], su);
                    su = fmaf(y4.z, sh.j.P[(k + 2) * 36 + j], su);
                    su = fmaf(y4.w, sh.j.P[(k + 3) * 36 + j], su);
                    sv = fmaf(p4.x, sh.j.Z[(k + 0) * 36 + j], sv);
                    sv = fmaf(p4.y, sh.j.Z[(k + 1) * 36 + j], sv);
                    sv = fmaf(p4.z, sh.j.Z[(k + 2) * 36 + j], sv);
                    sv = fmaf(p4.w, sh.j.Z[(k + 3) * 36 + j], sv);
                }
                U[u] = fmaf(-0.5f, su, 1.5f * sh.j.Y[i * 36 + j]);
                V[u] = fmaf(-0.5f, sv, 1.5f * sh.j.Z[i * 36 + j]);
            }
            __syncthreads();
#pragma unroll
            for (int u = 0; u < 4; u++) {
                int e = t * 4 + u;
                int i = e >> 5, j = e & 31;
                sh.j.Y[i * 36 + j] = U[u];
                sh.j.Z[i * 36 + j] = V[u];
            }
            __syncthreads();
        }
#pragma unroll
        for (int u = 0; u < 4; u++) {
            int e = t * 4 + u;
            g_M[e] = sh.j.Z[(e >> 5) * 36 + (e & 31)];
        }
        return;
    }

    // ---------------- emb blocks: wave = (64 nodes, one p); W in LDS ----------------
    for (int idx = t; idx < 96 * 64; idx += 256) sh.w[idx] = W[idx];
    __syncthreads();                    // all threads reach this before any return

    int wg = (blockIdx.x - 1) * 4 + (t >> 6);
    if (wg >= EMB_WAVES) return;
    int p = wg % 3;                     // wave-uniform at runtime -> HW broadcast reads
    int node = (wg / 3) * 64 + (t & 63);
    if (node >= N_NODES) return;

    float x[64];
    const float4* f4 = reinterpret_cast<const float4*>(feat + (size_t)node * 64);
#pragma unroll
    for (int c = 0; c < 16; c++) {
        float4 v = f4[c];
        x[c * 4 + 0] = v.x; x[c * 4 + 1] = v.y; x[c * 4 + 2] = v.z; x[c * 4 + 3] = v.w;
    }
    float ssum = 0.f;
#pragma unroll
    for (int i = 0; i < 64; i++) ssum = fmaf(x[i], x[i], ssum);
    float inv = 1.0f / fmaxf(sqrtf(ssum), EPS_F);
#pragma unroll
    for (int i = 0; i < 64; i++) x[i] *= inv;      // normalize once

    float a[32];
#pragma unroll
    for (int h = 0; h < 32; h++) {                 // 32 dots for this wave's p-slice
        const float4* wr = reinterpret_cast<const float4*>(&sh.w[(h * 3 + p) << 6]);
        float d = 0.f;
#pragma unroll
        for (int i = 0; i < 16; i++) {
            float4 w4 = wr[i];                     // uniform-broadcast LDS read
            d = fmaf(x[i * 4 + 0], w4.x, d);
            d = fmaf(x[i * 4 + 1], w4.y, d);
            d = fmaf(x[i * 4 + 2], w4.z, d);
            d = fmaf(x[i * 4 + 3], w4.w, d);
        }
        a[h] = d;
    }
    unsigned int u[16];
#pragma unroll
    for (int k = 0; k < 16; k++) {
        unsigned int lo = __half_as_ushort(__float2half(a[2 * k]));
        unsigned int hi = __half_as_ushort(__float2half(a[2 * k + 1]));
        u[k] = (hi << 16) | lo;
    }
    int4* dst = reinterpret_cast<int4*>(&g_embh[(size_t)node * EMB_STRIDE + p * HID]);
    dst[0] = make_int4(u[0],  u[1],  u[2],  u[3]);
    dst[1] = make_int4(u[4],  u[5],  u[6],  u[7]);
    dst[2] = make_int4(u[8],  u[9],  u[10], u[11]);
    dst[3] = make_int4(u[12], u[13], u[14], u[15]);
}

// ---------------- gather + kappa + segment-sum + whiten (wave per node) ----------------
__global__ __launch_bounds__(256) void k_pool(const int* __restrict__ paths,
                                              const int* __restrict__ ksz,
                                              float* __restrict__ out) {
    __shared__ float Ml[HID * HID];
    for (int idx = threadIdx.x; idx < HID * HID; idx += 256) Ml[idx] = g_M[idx];
    __syncthreads();

    int lane = threadIdx.x & 63;
    int half = lane >> 5;
    int j = lane & 31;
    int node = blockIdx.x * 4 + (threadIdx.x >> 6);   // grid exactly N_NODES/4 blocks
    const __half* eb = g_embh;

    int off = g_offs[node];
    int ks  = ksz[node];
    float pooled = 0.f;

    if (ks == 16) {
        // fast path: half-wave owns 8 paths; all 24 gathers issued before any consume
        const int* pb = paths + (size_t)(off + (half << 3)) * 3;
        int ix[24];
#pragma unroll
        for (int u = 0; u < 24; u++) ix[u] = pb[u];
        __half v0[8], v1[8], v2[8];
#pragma unroll
        for (int q = 0; q < 8; q++) {
            v0[q] = eb[(size_t)ix[3 * q + 0] * EMB_STRIDE + j];
            v1[q] = eb[(size_t)ix[3 * q + 1] * EMB_STRIDE + HID + j];
            v2[q] = eb[(size_t)ix[3 * q + 2] * EMB_STRIDE + 2 * HID + j];
        }
#pragma unroll
        for (int q = 0; q < 8; q++) {
            float e = __half2float(v0[q]) + __half2float(v1[q]) + __half2float(v2[q]);
            pooled += __expf(fmaf(e, 4.0f / 3.0f, -4.0f));
        }
    } else {
        // generic path (exact repeat/segment semantics for any ks)
        for (int pi = half; pi < ks; pi += 2) {
            size_t pp = (size_t)(off + pi) * 3;
            int i0 = paths[pp + 0], i1 = paths[pp + 1], i2 = paths[pp + 2];
            float e = __half2float(eb[(size_t)i0 * EMB_STRIDE + j])
                    + __half2float(eb[(size_t)i1 * EMB_STRIDE + HID + j])
                    + __half2float(eb[(size_t)i2 * EMB_STRIDE + 2 * HID + j]);
            pooled += __expf(fmaf(e, 4.0f / 3.0f, -4.0f));
        }
    }

    pooled += __shfl_xor(pooled, 32);       // combine the two half-waves
    // whiten: out[node][j] = sum_k pooled[k] * M[k][j]
    float o = 0.f;
#pragma unroll
    for (int k = 0; k < 32; k++)
        o = fmaf(__shfl(pooled, k), Ml[k * 32 + j], o);
    if (half == 0) out[(size_t)node * HID + j] = o;
}

extern "C" void kernel_launch(void* const* d_in, const int* in_sizes, int n_in,
                              void* d_out, int out_size, void* d_ws, size_t ws_size,
                              hipStream_t stream) {
    const float* feat  = (const float*)d_in[0];
    const int*   paths = (const int*)d_in[1];
    const int*   ksz   = (const int*)d_in[2];
    const float* W     = (const float*)d_in[3];
    float*       out   = (float*)d_out;

    k_scan1<<<SCAN_NB, SCAN_TPB, 0, stream>>>(ksz);
    k_scan2<<<1, 64, 0, stream>>>();
    k_scan3<<<SCAN_NB, SCAN_TPB, 0, stream>>>(ksz);

    k_embns<<<EMB_BLOCKS + 1, 256, 0, stream>>>(feat, W);

    k_pool<<<N_NODES / 4, 256, 0, stream>>>(paths, ksz, out);
}

// Round 14
// 219.981 us; speedup vs baseline: 2.3169x; 1.2257x over previous
//
#include <hip/hip_runtime.h>
#include <hip/hip_fp16.h>
#include <math.h>

#define N_NODES    100000
#define N_PATHS    1600000
#define PATH_SZ    3
#define IN_SZ      64
#define HID        32
#define EMB_STRIDE 96          // PATH_SZ * HID (halves)
#define EPS_F      1e-4f

#define SCAN_TPB   256
#define SCAN_IPT   8
#define SCAN_CHUNK (SCAN_TPB * SCAN_IPT)                        // 2048
#define SCAN_NB    ((N_NODES + SCAN_CHUNK - 1) / SCAN_CHUNK)   // 49

#define EMB_MBLOCKS ((N_NODES + 63) / 64)                      // 1563 (64 nodes per block)

typedef _Float16 half8 __attribute__((ext_vector_type(8)));
typedef float    f32x4 __attribute__((ext_vector_type(4)));

// ---- static device scratch ----
__device__ __half g_embh[(size_t)N_NODES * EMB_STRIDE];  // 19.2 MB fp16
__device__ float  g_M[HID * HID];                        // gram^{-1/2}
__device__ int    g_offs[N_NODES];
__device__ int    g_bsum[SCAN_NB];
__device__ int    g_boff[SCAN_NB];

static __device__ __forceinline__ unsigned int pk2(float lo, float hi) {
    return ((unsigned int)__half_as_ushort(__float2half(hi)) << 16) |
           (unsigned int)__half_as_ushort(__float2half(lo));
}

// ---------------- multi-block prefix-sum of kernel_size -> g_offs ----------------
__global__ __launch_bounds__(SCAN_TPB) void k_scan1(const int* __restrict__ ksz) {
    __shared__ int red[SCAN_TPB];
    int b = blockIdx.x, t = threadIdx.x;
    int base = b * SCAN_CHUNK + t * SCAN_IPT;
    int s = 0;
#pragma unroll
    for (int u = 0; u < SCAN_IPT; u++) {
        int idx = base + u;
        if (idx < N_NODES) s += ksz[idx];
    }
    red[t] = s;
    __syncthreads();
    for (int d = SCAN_TPB >> 1; d > 0; d >>= 1) {
        if (t < d) red[t] += red[t + d];
        __syncthreads();
    }
    if (t == 0) g_bsum[b] = red[0];
}

// 64-lane shuffle scan over the 49 block sums
__global__ void k_scan2() {
    int t = threadIdx.x;                 // 64 threads
    int v = (t < SCAN_NB) ? g_bsum[t] : 0;
    int orig = v;
#pragma unroll
    for (int d = 1; d < 64; d <<= 1) {
        int o = __shfl_up(v, d);
        if (t >= d) v += o;
    }
    if (t < SCAN_NB) g_boff[t] = v - orig;   // exclusive prefix
}

__global__ __launch_bounds__(SCAN_TPB) void k_scan3(const int* __restrict__ ksz) {
    __shared__ int sc[SCAN_TPB];
    int b = blockIdx.x, t = threadIdx.x;
    int base = b * SCAN_CHUNK + t * SCAN_IPT;
    int v[SCAN_IPT];
    int s = 0;
#pragma unroll
    for (int u = 0; u < SCAN_IPT; u++) {
        int idx = base + u;
        v[u] = (idx < N_NODES) ? ksz[idx] : 0;
        s += v[u];
    }
    sc[t] = s;
    __syncthreads();
    for (int d = 1; d < SCAN_TPB; d <<= 1) {
        int a = (t >= d) ? sc[t - d] : 0;
        __syncthreads();
        sc[t] += a;
        __syncthreads();
    }
    int incl = sc[t];
    int run = g_boff[b] + (incl - s);   // exclusive prefix for this thread
#pragma unroll
    for (int u = 0; u < SCAN_IPT; u++) {
        int idx = base + u;
        if (idx < N_NODES) g_offs[idx] = run;
        run += v[u];
    }
}

// ---------------- fused: MFMA emb GEMM (blocks>=1) + gram/NS (block 0) ----------------
union ShE {
    struct {
        __half Bt[96 * 72];      // Bt[c][k]: transposed fp16 weights, stride 72 (2-way-free banks)
        __half outS[64 * 104];   // C staging for coalesced stores, stride 104
    } e;                         // 27.1 KB
    struct {
        float w[96 * 68];        // padded fp32 W for gram
        float Y[32 * 36];
        float Z[32 * 36];
        float P[32 * 36];
    } j;                         // 39.9 KB
};

__global__ __launch_bounds__(256) void k_embns(const float* __restrict__ feat,
                                               const float* __restrict__ W) {
    __shared__ ShE sh;
    int t = threadIdx.x;

    if (blockIdx.x == 0) {
        // ---- stage W padded (stride 68) ----
        for (int idx = t; idx < 96 * 64; idx += 256) {
            int r = idx >> 6, c = idx & 63;
            sh.j.w[r * 68 + c] = W[idx];
        }
        __syncthreads();
        // ---- gram = kappa(W.Wt/3) into Y; Z = I ----
#pragma unroll
        for (int u = 0; u < 4; u++) {
            int e = t * 4 + u;
            int h = e >> 5, g = e & 31;
            float d = 0.f;
            for (int pi = 0; pi < 3; pi++) {
                const float4* r0 = reinterpret_cast<const float4*>(&sh.j.w[(h * 3 + pi) * 68]);
                const float4* r1 = reinterpret_cast<const float4*>(&sh.j.w[(g * 3 + pi) * 68]);
#pragma unroll
                for (int i = 0; i < 16; i++) {
                    float4 a = r0[i], b = r1[i];
                    d = fmaf(a.x, b.x, d); d = fmaf(a.y, b.y, d);
                    d = fmaf(a.z, b.z, d); d = fmaf(a.w, b.w, d);
                }
            }
            sh.j.Y[h * 36 + g] = __expf(fmaf(d, 4.0f / 3.0f, -4.0f));
            sh.j.Z[h * 36 + g] = (h == g) ? 1.0f : 0.0f;
        }
        __syncthreads();
        // ---- coupled NS, 5 iters: P=Z*Y; Y<-1.5Y-0.5*(Y*P); Z<-1.5Z-0.5*(P*Z) ----
        for (int it = 0; it < 5; it++) {
#pragma unroll
            for (int u = 0; u < 4; u++) {
                int e = t * 4 + u;
                int i = e >> 5, j = e & 31;
                const float4* zr = reinterpret_cast<const float4*>(&sh.j.Z[i * 36]);
                float p = 0.f;
#pragma unroll
                for (int k8 = 0; k8 < 8; k8++) {
                    float4 z4 = zr[k8];
                    int k = k8 * 4;
                    p = fmaf(z4.x, sh.j.Y[(k + 0) * 36 + j], p);
                    p = fmaf(z4.y, sh.j.Y[(k + 1) * 36 + j], p);
                    p = fmaf(z4.z, sh.j.Y[(k + 2) * 36 + j], p);
                    p = fmaf(z4.w, sh.j.Y[(k + 3) * 36 + j], p);
                }
                sh.j.P[i * 36 + j] = p;
            }
            __syncthreads();
            float U[4], V[4];
#pragma unroll
            for (int u = 0; u < 4; u++) {
                int e = t * 4 + u;
                int i = e >> 5, j = e & 31;
                const float4* yr = reinterpret_cast<const float4*>(&sh.j.Y[i * 36]);
                const float4* pr = reinterpret_cast<const float4*>(&sh.j.P[i * 36]);
                float su = 0.f, sv = 0.f;
#pragma unroll
                for (int k8 = 0; k8 < 8; k8++) {
                    float4 y4 = yr[k8], p4 = pr[k8];
                    int k = k8 * 4;
                    su = fmaf(y4.x, sh.j.P[(k + 0) * 36 + j], su);
                    su = fmaf(y4.y, sh.j.P[(k + 1) * 36 + j], su);
                    su = fmaf(y4.z, sh.j.P[(k + 2) * 36 + j], su);
                    su = fmaf(y4.w, sh.j.P[(k + 3) * 36 + j], su);
                    sv = fmaf(p4.x, sh.j.Z[(k + 0) * 36 + j], sv);
                    sv = fmaf(p4.y, sh.j.Z[(k + 1) * 36 + j], sv);
                    sv = fmaf(p4.z, sh.j.Z[(k + 2) * 36 + j], sv);
                    sv = fmaf(p4.w, sh.j.Z[(k + 3) * 36 + j], sv);
                }
                U[u] = fmaf(-0.5f, su, 1.5f * sh.j.Y[i * 36 + j]);
                V[u] = fmaf(-0.5f, sv, 1.5f * sh.j.Z[i * 36 + j]);
            }
            __syncthreads();
#pragma unroll
            for (int u = 0; u < 4; u++) {
                int e = t * 4 + u;
                int i = e >> 5, j = e & 31;
                sh.j.Y[i * 36 + j] = U[u];
                sh.j.Z[i * 36 + j] = V[u];
            }
            __syncthreads();
        }
#pragma unroll
        for (int u = 0; u < 4; u++) {
            int e = t * 4 + u;
            g_M[e] = sh.j.Z[(e >> 5) * 36 + (e & 31)];
        }
        return;
    }

    // ---------------- emb MFMA blocks: 64 nodes x 96 cols per block ----------------
    // stage Bt[c][k] = fp16(W[(c&31)*3 + (c>>5)][k]); stored col c = p*32+h
    for (int item = t; item < 96 * 8; item += 256) {
        int c = item >> 3, kc = item & 7;
        int r = (c & 31) * 3 + (c >> 5);
        const float4* ws = reinterpret_cast<const float4*>(W + (r << 6) + (kc << 3));
        float4 w0 = ws[0], w1 = ws[1];
        *reinterpret_cast<int4*>(&sh.e.Bt[c * 72 + (kc << 3)]) =
            make_int4(pk2(w0.x, w0.y), pk2(w0.z, w0.w), pk2(w1.x, w1.y), pk2(w1.z, w1.w));
    }
    __syncthreads();

    int w = t >> 6, l = t & 63;
    int q = l >> 4;                     // k-quarter: A-frag k = q*8 + j (+ kstep*32)
    int mrow = l & 15;                  // A-frag row / B-frag col / D col
    int nodeBase = (blockIdx.x - 1) * 64;
    int node = nodeBase + w * 16 + mrow;
    bool ok = (node < N_NODES);

    // A-fragments straight from global feat; normalize via 4-lane shuffle reduce
    float xa[8], xb[8];
    if (ok) {
        const float4* fr = reinterpret_cast<const float4*>(feat + (size_t)node * 64 + q * 8);
        float4 v0 = fr[0], v1 = fr[1];
        const float4* fr2 = reinterpret_cast<const float4*>(feat + (size_t)node * 64 + 32 + q * 8);
        float4 v2 = fr2[0], v3 = fr2[1];
        xa[0] = v0.x; xa[1] = v0.y; xa[2] = v0.z; xa[3] = v0.w;
        xa[4] = v1.x; xa[5] = v1.y; xa[6] = v1.z; xa[7] = v1.w;
        xb[0] = v2.x; xb[1] = v2.y; xb[2] = v2.z; xb[3] = v2.w;
        xb[4] = v3.x; xb[5] = v3.y; xb[6] = v3.z; xb[7] = v3.w;
    } else {
#pragma unroll
        for (int j = 0; j < 8; j++) { xa[j] = 0.f; xb[j] = 0.f; }
    }
    float ssum = 0.f;
#pragma unroll
    for (int j = 0; j < 8; j++) ssum = fmaf(xa[j], xa[j], fmaf(xb[j], xb[j], ssum));
    ssum += __shfl_xor(ssum, 16);
    ssum += __shfl_xor(ssum, 32);       // 4 lanes {q=0..3} of one node combined
    float inv = 1.0f / fmaxf(sqrtf(ssum), EPS_F);

    half8 a0, a1;
#pragma unroll
    for (int j = 0; j < 8; j++) {
        a0[j] = (_Float16)(xa[j] * inv);
        a1[j] = (_Float16)(xb[j] * inv);
    }

    f32x4 acc[6];
#pragma unroll
    for (int n6 = 0; n6 < 6; n6++) acc[n6] = (f32x4){0.f, 0.f, 0.f, 0.f};

    // K-step 0 (k=0..31) then K-step 1 (k=32..63); B-frag: col=mrow, k=(q*8..+7)+32*kstep
#pragma unroll
    for (int n6 = 0; n6 < 6; n6++) {
        half8 b0 = *reinterpret_cast<const half8*>(&sh.e.Bt[(n6 * 16 + mrow) * 72 + (q << 3)]);
        acc[n6] = __builtin_amdgcn_mfma_f32_16x16x32_f16(a0, b0, acc[n6], 0, 0, 0);
    }
#pragma unroll
    for (int n6 = 0; n6 < 6; n6++) {
        half8 b1 = *reinterpret_cast<const half8*>(&sh.e.Bt[(n6 * 16 + mrow) * 72 + 32 + (q << 3)]);
        acc[n6] = __builtin_amdgcn_mfma_f32_16x16x32_f16(a1, b1, acc[n6], 0, 0, 0);
    }

    // C/D: col = lane&15 (=mrow), row = (lane>>4)*4 + reg (=q*4+reg). Stage to LDS.
#pragma unroll
    for (int n6 = 0; n6 < 6; n6++) {
#pragma unroll
        for (int r4 = 0; r4 < 4; r4++) {
            int nl = w * 16 + q * 4 + r4;
            sh.e.outS[nl * 104 + n6 * 16 + mrow] = __float2half(acc[n6][r4]);
        }
    }
    __syncthreads();
    // coalesced 16-B stores: 64 rows x 12 int4
    for (int item = t; item < 64 * 12; item += 256) {
        int nl = item / 12, c4 = item - nl * 12;
        int nn = nodeBase + nl;
        if (nn < N_NODES) {
            int4 v = *reinterpret_cast<const int4*>(&sh.e.outS[nl * 104 + (c4 << 3)]);
            *reinterpret_cast<int4*>(&g_embh[(size_t)nn * EMB_STRIDE + (c4 << 3)]) = v;
        }
    }
}

// ---------------- gather + kappa + segment-sum + whiten (wave per node) ----------------
__global__ __launch_bounds__(256) void k_pool(const int* __restrict__ paths,
                                              const int* __restrict__ ksz,
                                              float* __restrict__ out) {
    __shared__ float Ml[HID * HID];
    for (int idx = threadIdx.x; idx < HID * HID; idx += 256) Ml[idx] = g_M[idx];
    __syncthreads();

    int lane = threadIdx.x & 63;
    int half = lane >> 5;
    int j = lane & 31;
    int node = blockIdx.x * 4 + (threadIdx.x >> 6);   // grid exactly N_NODES/4 blocks
    const __half* eb = g_embh;

    int off = g_offs[node];
    int ks  = ksz[node];
    float pooled = 0.f;

    if (ks == 16) {
        // fast path: half-wave owns 8 paths; all 24 gathers issued before any consume
        const int* pb = paths + (size_t)(off + (half << 3)) * 3;
        int ix[24];
#pragma unroll
        for (int u = 0; u < 24; u++) ix[u] = pb[u];
        __half v0[8], v1[8], v2[8];
#pragma unroll
        for (int q = 0; q < 8; q++) {
            v0[q] = eb[(size_t)ix[3 * q + 0] * EMB_STRIDE + j];
            v1[q] = eb[(size_t)ix[3 * q + 1] * EMB_STRIDE + HID + j];
            v2[q] = eb[(size_t)ix[3 * q + 2] * EMB_STRIDE + 2 * HID + j];
        }
#pragma unroll
        for (int q = 0; q < 8; q++) {
            float e = __half2float(v0[q]) + __half2float(v1[q]) + __half2float(v2[q]);
            pooled += __expf(fmaf(e, 4.0f / 3.0f, -4.0f));
        }
    } else {
        // generic path (exact repeat/segment semantics for any ks)
        for (int pi = half; pi < ks; pi += 2) {
            size_t pp = (size_t)(off + pi) * 3;
            int i0 = paths[pp + 0], i1 = paths[pp + 1], i2 = paths[pp + 2];
            float e = __half2float(eb[(size_t)i0 * EMB_STRIDE + j])
                    + __half2float(eb[(size_t)i1 * EMB_STRIDE + HID + j])
                    + __half2float(eb[(size_t)i2 * EMB_STRIDE + 2 * HID + j]);
            pooled += __expf(fmaf(e, 4.0f / 3.0f, -4.0f));
        }
    }

    pooled += __shfl_xor(pooled, 32);       // combine the two half-waves
    // whiten: out[node][j] = sum_k pooled[k] * M[k][j]
    float o = 0.f;
#pragma unroll
    for (int k = 0; k < 32; k++)
        o = fmaf(__shfl(pooled, k), Ml[k * 32 + j], o);
    if (half == 0) out[(size_t)node * HID + j] = o;
}

extern "C" void kernel_launch(void* const* d_in, const int* in_sizes, int n_in,
                              void* d_out, int out_size, void* d_ws, size_t ws_size,
                              hipStream_t stream) {
    const float* feat  = (const float*)d_in[0];
    const int*   paths = (const int*)d_in[1];
    const int*   ksz   = (const int*)d_in[2];
    const float* W     = (const float*)d_in[3];
    float*       out   = (float*)d_out;

    k_scan1<<<SCAN_NB, SCAN_TPB, 0, stream>>>(ksz);
    k_scan2<<<1, 64, 0, stream>>>();
    k_scan3<<<SCAN_NB, SCAN_TPB, 0, stream>>>(ksz);

    k_embns<<<EMB_MBLOCKS + 1, 256, 0, stream>>>(feat, W);

    k_pool<<<N_NODES / 4, 256, 0, stream>>>(paths, ksz, out);
}